// Round 3
// baseline (153.577 us; speedup 1.0000x reference)
//
#include <hip/hip_runtime.h>
#include <hip/hip_cooperative_groups.h>

namespace cg = cooperative_groups;

#define NC 8                  // NUM_CLASSES
#define XBLK 256              // blocks per batch
#define NB 4                  // batch size
#define GRID (XBLK * NB)      // 1024 blocks, 4 waves each -> 16 waves/CU, co-resident
#define NROWS (NB * 3 * NC)   // 96 counter rows

// Fused: per-(batch,class) histogram counts -> grid sync -> block 0 finalizes.
// P = #{pred==c}, L = #{label==c}, I = #{pred==label==c};
// out[c] = mean_b 2I/(P+L+1e-10).
__global__ void __launch_bounds__(256) dice_fused_kernel(
    const int* __restrict__ pred, const int* __restrict__ label,
    unsigned int* __restrict__ ws, float* __restrict__ out, int nvec_per_batch)
{
    const int xblk = blockIdx.x & (XBLK - 1);
    const int b    = blockIdx.x >> 8;
    const int4* p4 = reinterpret_cast<const int4*>(pred) + (size_t)b * nvec_per_batch;
    const int4* l4 = reinterpret_cast<const int4*>(label) + (size_t)b * nvec_per_batch;

    // 8 classes x 8-bit fields in one 64-bit accumulator; per-thread element
    // count is 32 (< 255) so fields can't overflow.
    unsigned long long packP = 0, packL = 0, packI = 0;

    const int stride = XBLK * 256;
    #pragma unroll 2
    for (int i = xblk * 256 + threadIdx.x; i < nvec_per_batch; i += stride) {
        int4 pv = p4[i];
        int4 lv = l4[i];
        int pe[4] = {pv.x, pv.y, pv.z, pv.w};
        int le[4] = {lv.x, lv.y, lv.z, lv.w};
        #pragma unroll
        for (int j = 0; j < 4; ++j) {
            unsigned long long sp = 1ULL << (pe[j] * 8);
            unsigned long long sl = 1ULL << (le[j] * 8);
            packP += sp;
            packL += sl;
            packI += (pe[j] == le[j]) ? sp : 0ULL;
        }
    }

    // Unpack to 24 per-class counts (static indexing after unroll).
    unsigned cnt[3 * NC];
    #pragma unroll
    for (int c = 0; c < NC; ++c) {
        cnt[c]          = (unsigned)((packP >> (8 * c)) & 0xFFULL);
        cnt[NC + c]     = (unsigned)((packL >> (8 * c)) & 0xFFULL);
        cnt[2 * NC + c] = (unsigned)((packI >> (8 * c)) & 0xFFULL);
    }

    // Wave64 tree reduction.
    #pragma unroll
    for (int k = 0; k < 3 * NC; ++k) {
        #pragma unroll
        for (int off = 32; off > 0; off >>= 1)
            cnt[k] += __shfl_down(cnt[k], off, 64);
    }

    // Cross-wave reduction in LDS, then per-block partial writes (transposed
    // layout so the finalize reads coalesce). No atomics on global, no init.
    __shared__ unsigned s[3 * NC];
    if (threadIdx.x < 3 * NC) s[threadIdx.x] = 0;
    __syncthreads();
    if ((threadIdx.x & 63) == 0) {
        #pragma unroll
        for (int k = 0; k < 3 * NC; ++k)
            atomicAdd(&s[k], cnt[k]);
    }
    __syncthreads();
    if (threadIdx.x < 3 * NC)
        ws[(b * 3 * NC + threadIdx.x) * XBLK + xblk] = s[threadIdx.x];

    // Make partials visible device-wide (cross-XCD), then grid barrier.
    __threadfence();
    cg::this_grid().sync();

    // Block 0: reduce 96 rows x 256 partials, compute the 8 dice means.
    if (blockIdx.x == 0) {
        __shared__ float tot[NROWS];
        const int wave = threadIdx.x >> 6;   // 0..3
        const int lane = threadIdx.x & 63;

        for (int r = wave; r < NROWS; r += 4) {
            const uint4* p = reinterpret_cast<const uint4*>(ws + (size_t)r * XBLK);
            uint4 v = p[lane];               // 64 lanes x 4 = 256 partials
            unsigned sum = v.x + v.y + v.z + v.w;
            #pragma unroll
            for (int off = 32; off > 0; off >>= 1)
                sum += __shfl_down(sum, off, 64);
            if (lane == 0) tot[r] = (float)sum;
        }
        __syncthreads();

        if (threadIdx.x < NC) {
            const int c = threadIdx.x;
            float acc = 0.0f;
            #pragma unroll
            for (int bb = 0; bb < NB; ++bb) {
                float P = tot[bb * 3 * NC + c];
                float L = tot[bb * 3 * NC + NC + c];
                float I = tot[bb * 3 * NC + 2 * NC + c];
                acc += 2.0f * I / (P + L + 1e-10f);
            }
            out[c] = acc * (1.0f / NB);
        }
    }
}

extern "C" void kernel_launch(void* const* d_in, const int* in_sizes, int n_in,
                              void* d_out, int out_size, void* d_ws, size_t ws_size,
                              hipStream_t stream)
{
    const int* pred  = (const int*)d_in[0];
    const int* label = (const int*)d_in[1];
    float* out = (float*)d_out;
    unsigned int* ws = (unsigned int*)d_ws;

    const int n = in_sizes[0];          // 4*1*128*128*128 = 8388608
    const int per_batch = n / NB;       // 2097152
    int nvec = per_batch / 4;           // 524288 int4 vectors per batch

    void* args[] = {(void*)&pred, (void*)&label, (void*)&ws, (void*)&out, (void*)&nvec};
    hipLaunchCooperativeKernel((void*)dice_fused_kernel,
                               dim3(GRID), dim3(256), args, 0, stream);
}

// Round 4
// 41.197 us; speedup vs baseline: 3.7279x; 3.7279x over previous
//
#include <hip/hip_runtime.h>

#define NC 8                  // NUM_CLASSES
#define XBLK 256              // blocks per batch
#define NB 4                  // batch size
#define GRID_X (XBLK * NB)    // 1024 blocks
#define NCNT (NB * 3 * NC)    // 96 global counters
// ws layout: ws[0..95] = counters (P[b][c], L[b][c], I[b][c] per batch), ws[96] = ticket

// Fused single kernel: per-(batch,class) histogram -> device-scope atomic
// accumulate -> last-arriving block (atomic ticket) computes the 8 outputs.
// P = #{pred==c}, L = #{label==c}, I = #{pred==label==c};
// out[c] = mean_b 2I/(P+L+1e-10).
__global__ void __launch_bounds__(256) dice_fused_kernel(
    const int* __restrict__ pred, const int* __restrict__ label,
    unsigned int* __restrict__ ws, float* __restrict__ out, int nvec_per_batch)
{
    const int xblk = blockIdx.x & (XBLK - 1);
    const int b    = blockIdx.x >> 8;
    const int4* p4 = reinterpret_cast<const int4*>(pred) + (size_t)b * nvec_per_batch;
    const int4* l4 = reinterpret_cast<const int4*>(label) + (size_t)b * nvec_per_batch;

    // 8 classes x 8-bit fields in one 64-bit accumulator; per-thread element
    // count is 32 (< 255) so fields can't overflow.
    unsigned long long packP = 0, packL = 0, packI = 0;

    const int stride = XBLK * 256;
    #pragma unroll 2
    for (int i = xblk * 256 + threadIdx.x; i < nvec_per_batch; i += stride) {
        int4 pv = p4[i];
        int4 lv = l4[i];
        int pe[4] = {pv.x, pv.y, pv.z, pv.w};
        int le[4] = {lv.x, lv.y, lv.z, lv.w};
        #pragma unroll
        for (int j = 0; j < 4; ++j) {
            unsigned long long sp = 1ULL << (pe[j] * 8);
            unsigned long long sl = 1ULL << (le[j] * 8);
            packP += sp;
            packL += sl;
            packI += (pe[j] == le[j]) ? sp : 0ULL;
        }
    }

    // Unpack to 24 per-class counts (static indexing after unroll).
    unsigned cnt[3 * NC];
    #pragma unroll
    for (int c = 0; c < NC; ++c) {
        cnt[c]          = (unsigned)((packP >> (8 * c)) & 0xFFULL);
        cnt[NC + c]     = (unsigned)((packL >> (8 * c)) & 0xFFULL);
        cnt[2 * NC + c] = (unsigned)((packI >> (8 * c)) & 0xFFULL);
    }

    // Wave64 tree reduction.
    #pragma unroll
    for (int k = 0; k < 3 * NC; ++k) {
        #pragma unroll
        for (int off = 32; off > 0; off >>= 1)
            cnt[k] += __shfl_down(cnt[k], off, 64);
    }

    // Cross-wave reduction in LDS.
    __shared__ unsigned s[3 * NC];
    if (threadIdx.x < 3 * NC) s[threadIdx.x] = 0;
    __syncthreads();
    if ((threadIdx.x & 63) == 0) {
        #pragma unroll
        for (int k = 0; k < 3 * NC; ++k)
            atomicAdd(&s[k], cnt[k]);
    }
    __syncthreads();

    // Device-scope (coherent) accumulation of this block's 24 partials.
    if (threadIdx.x < 3 * NC)
        atomicAdd(&ws[b * 3 * NC + threadIdx.x], s[threadIdx.x]);
    __syncthreads();               // drains the atomics (vmcnt 0 before barrier)

    // Ticket: exactly one block sees old == GRID_X-1, after all others'
    // counter atomics have completed.
    __shared__ int last;
    if (threadIdx.x == 0) {
        __threadfence();
        unsigned old = atomicAdd(&ws[NCNT], 1u);
        last = (old == GRID_X - 1) ? 1 : 0;
    }
    __syncthreads();
    if (!last) return;

    // Last block: coherent read-back of the 96 totals, compute 8 dice means.
    __threadfence();
    __shared__ float tot[NCNT];
    if (threadIdx.x < NCNT)
        tot[threadIdx.x] = (float)atomicAdd(&ws[threadIdx.x], 0u);
    __syncthreads();

    if (threadIdx.x < NC) {
        const int c = threadIdx.x;
        float acc = 0.0f;
        #pragma unroll
        for (int bb = 0; bb < NB; ++bb) {
            float P = tot[bb * 3 * NC + c];
            float L = tot[bb * 3 * NC + NC + c];
            float I = tot[bb * 3 * NC + 2 * NC + c];
            acc += 2.0f * I / (P + L + 1e-10f);
        }
        out[c] = acc * (1.0f / NB);
    }
}

extern "C" void kernel_launch(void* const* d_in, const int* in_sizes, int n_in,
                              void* d_out, int out_size, void* d_ws, size_t ws_size,
                              hipStream_t stream)
{
    const int* pred  = (const int*)d_in[0];
    const int* label = (const int*)d_in[1];
    float* out = (float*)d_out;
    unsigned int* ws = (unsigned int*)d_ws;

    const int n = in_sizes[0];          // 4*1*128*128*128 = 8388608
    const int per_batch = n / NB;       // 2097152
    int nvec = per_batch / 4;           // 524288 int4 vectors per batch

    // Zero 96 counters + ticket (388 B) — cheap single fill node.
    hipMemsetAsync(ws, 0, (size_t)(NCNT + 1) * sizeof(unsigned int), stream);

    dice_fused_kernel<<<dim3(GRID_X), dim3(256), 0, stream>>>(pred, label, ws, out, nvec);
}

// Round 5
// 26.949 us; speedup vs baseline: 5.6988x; 1.5287x over previous
//
#include <hip/hip_runtime.h>

#define NC 8                   // NUM_CLASSES
#define NB 4                   // batch size
#define XBLK 512               // blocks per batch -> grid (512,4) = 2048 blocks = 8/CU = 32 waves/CU
#define TPB 256
#define STRIDE (XBLK * TPB)    // 131072 int4 vectors per sweep
#define NROWS (NB * 3 * NC)    // 96 partial rows

// Per-(batch,class) counts: P = #{pred==c}, L = #{label==c}, I = #{pred==label==c}.
// Each block writes 24 partials to ws[(b*24+k)*XBLK + xblk] (transposed so the
// finalize reads coalesce). No atomics, no ws init needed: every slot written
// unconditionally every call.
__global__ void __launch_bounds__(TPB) dice_count_kernel(
    const int* __restrict__ pred, const int* __restrict__ label,
    unsigned int* __restrict__ ws, int nvec_per_batch)
{
    const int xblk = blockIdx.x;
    const int b    = blockIdx.y;
    const int4* p4 = reinterpret_cast<const int4*>(pred) + (size_t)b * nvec_per_batch;
    const int4* l4 = reinterpret_cast<const int4*>(label) + (size_t)b * nvec_per_batch;

    // 8 classes x 8-bit fields in one 64-bit accumulator. Per-thread element
    // count is 16 for the target shape (4 int4) -- far below the 255 field cap.
    unsigned long long packP = 0, packL = 0, packI = 0;

    const int i0 = xblk * TPB + (int)threadIdx.x;
    int i = i0;

    // Main path: batch-issue 8 independent dwordx4 loads (4 pred + 4 label),
    // then consume -- maximizes loads in flight. For nvec=524288 this runs
    // exactly once per thread and the tail loop is never taken.
    for (; i + 3 * STRIDE < nvec_per_batch; i += 4 * STRIDE) {
        int4 pv[4], lv[4];
        #pragma unroll
        for (int u = 0; u < 4; ++u) {
            pv[u] = p4[i + u * STRIDE];
            lv[u] = l4[i + u * STRIDE];
        }
        #pragma unroll
        for (int u = 0; u < 4; ++u) {
            int pe[4] = {pv[u].x, pv[u].y, pv[u].z, pv[u].w};
            int le[4] = {lv[u].x, lv[u].y, lv[u].z, lv[u].w};
            #pragma unroll
            for (int j = 0; j < 4; ++j) {
                unsigned long long sp = 1ULL << (pe[j] * 8);
                unsigned long long sl = 1ULL << (le[j] * 8);
                packP += sp;
                packL += sl;
                packI += (pe[j] == le[j]) ? sp : 0ULL;
            }
        }
    }
    // Generic tail (unused for the target shape).
    for (; i < nvec_per_batch; i += STRIDE) {
        int4 pv = p4[i];
        int4 lv = l4[i];
        int pe[4] = {pv.x, pv.y, pv.z, pv.w};
        int le[4] = {lv.x, lv.y, lv.z, lv.w};
        #pragma unroll
        for (int j = 0; j < 4; ++j) {
            unsigned long long sp = 1ULL << (pe[j] * 8);
            unsigned long long sl = 1ULL << (le[j] * 8);
            packP += sp;
            packL += sl;
            packI += (pe[j] == le[j]) ? sp : 0ULL;
        }
    }

    // Unpack to 24 per-class counts (static indexing after unroll).
    unsigned cnt[3 * NC];
    #pragma unroll
    for (int c = 0; c < NC; ++c) {
        cnt[c]          = (unsigned)((packP >> (8 * c)) & 0xFFULL);
        cnt[NC + c]     = (unsigned)((packL >> (8 * c)) & 0xFFULL);
        cnt[2 * NC + c] = (unsigned)((packI >> (8 * c)) & 0xFFULL);
    }

    // Wave64 tree reduction.
    #pragma unroll
    for (int k = 0; k < 3 * NC; ++k) {
        #pragma unroll
        for (int off = 32; off > 0; off >>= 1)
            cnt[k] += __shfl_down(cnt[k], off, 64);
    }

    // Cross-wave reduction in LDS (4 waves), then per-block partial writes.
    __shared__ unsigned s[3 * NC];
    if (threadIdx.x < 3 * NC) s[threadIdx.x] = 0;
    __syncthreads();
    if ((threadIdx.x & 63) == 0) {
        #pragma unroll
        for (int k = 0; k < 3 * NC; ++k)
            atomicAdd(&s[k], cnt[k]);
    }
    __syncthreads();
    if (threadIdx.x < 3 * NC)
        ws[((size_t)b * 3 * NC + threadIdx.x) * XBLK + xblk] = s[threadIdx.x];
}

// 8 blocks (one per class) x 256 threads (wave = batch). Each wave reduces the
// class's P/L/I rows (512 partials each, read as uint4: 2 per lane per row),
// then computes dice[b]; thread 0 averages over batches.
__global__ void __launch_bounds__(TPB) dice_final_kernel(
    const unsigned int* __restrict__ ws, float* __restrict__ out)
{
    const int c    = blockIdx.x;
    const int b    = threadIdx.x >> 6;
    const int lane = threadIdx.x & 63;
    const uint4* base = reinterpret_cast<const uint4*>(ws);

    unsigned sums[3];
    uint4 v[3][2];
    #pragma unroll
    for (int k = 0; k < 3; ++k) {
        const uint4* row = base + (size_t)(b * 3 * NC + k * NC + c) * (XBLK / 4);
        v[k][0] = row[lane];
        v[k][1] = row[lane + 64];
    }
    #pragma unroll
    for (int k = 0; k < 3; ++k) {
        sums[k] = v[k][0].x + v[k][0].y + v[k][0].z + v[k][0].w
                + v[k][1].x + v[k][1].y + v[k][1].z + v[k][1].w;
        #pragma unroll
        for (int off = 32; off > 0; off >>= 1)
            sums[k] += __shfl_down(sums[k], off, 64);
    }

    __shared__ float dice[NB];
    if (lane == 0) {
        float P = (float)sums[0], L = (float)sums[1], I = (float)sums[2];
        dice[b] = 2.0f * I / (P + L + 1e-10f);
    }
    __syncthreads();
    if (threadIdx.x == 0)
        out[c] = 0.25f * (dice[0] + dice[1] + dice[2] + dice[3]);
}

extern "C" void kernel_launch(void* const* d_in, const int* in_sizes, int n_in,
                              void* d_out, int out_size, void* d_ws, size_t ws_size,
                              hipStream_t stream)
{
    const int* pred  = (const int*)d_in[0];
    const int* label = (const int*)d_in[1];
    float* out = (float*)d_out;
    unsigned int* ws = (unsigned int*)d_ws;

    const int n = in_sizes[0];          // 4*1*128*128*128 = 8388608
    const int per_batch = n / NB;       // 2097152
    int nvec = per_batch / 4;           // 524288 int4 vectors per batch

    dice_count_kernel<<<dim3(XBLK, NB), dim3(TPB), 0, stream>>>(pred, label, ws, nvec);
    dice_final_kernel<<<dim3(NC), dim3(TPB), 0, stream>>>(ws, out);
}